// Round 6
// baseline (49.995 us; speedup 1.0000x reference)
//
#include <hip/hip_runtime.h>

typedef float v4f __attribute__((ext_vector_type(4)));

// 45-tap palindromic filter, padded to 48 with zeros so every phase uses a
// uniform 12-tap loop: out phase p uses weight BASE48[4*j + 3 - p].
constexpr float BASE48[48] = {
    -0.00463495665f, -0.00363442646f, 3.84904063e-18f, 0.00576678319f, 0.0108358664f,
    0.010198079f, -9.31747402e-18f, -0.0175033181f, -0.0317660068f, -0.0284531643f,
    1.85181518e-17f, 0.0442450253f, 0.0771733386f, 0.067055491f, -2.85299239e-17f,
    -0.101548683f, -0.178708388f, -0.160004642f, 3.61741232e-17f, 0.287940558f,
    0.625431459f, 0.8970676f, 1.00107877f, 0.8970676f, 0.625431459f, 0.287940558f,
    3.61741232e-17f, -0.160004642f, -0.178708388f, -0.101548683f, -2.85299239e-17f,
    0.067055491f, 0.0771733386f, 0.0442450253f, 1.85181518e-17f, -0.0284531643f,
    -0.0317660068f, -0.0175033181f, -9.31747402e-18f, 0.010198079f, 0.0108358664f,
    0.00576678319f, 3.84904063e-18f, -0.00363442646f, -0.00463495665f,
    0.0f, 0.0f, 0.0f
};

// One block = 64x64 output tile of one (b,c) image. Vertical-first structure:
//   V-phase: read input columns straight from global (L2/L3-resident, no LDS
//            stage), compute vertical polyphase -> vtmp[64 out rows][27 cols]
//   barrier
//   H-phase: sliding-window horizontal polyphase from vtmp (b128 reads),
//            store final v4f directly to global.
// Per axis: out o -> phase p = o&3, m = o>>2; input i = m - 5 + j, j in [0,12),
// weight BASE48[4*j + 3 - p]. Halo cols = 64/4 + 11 = 27.
// LDS = 64*28*4 = 7.2 KB -> 8 blocks/CU (wave-capped). Grid 8192 = 4 rounds.
__launch_bounds__(256)
__global__ void upfirdn4_vh_kernel(const float* __restrict__ x,
                                   float* __restrict__ out) {
    constexpr int H = 128, W = 128, OW = 512, OH = 512;

    __shared__ float vtmp[64][28];   // 64 out rows x 27 halo cols (+1 pad)

    const int tid = threadIdx.x;
    const int bc  = blockIdx.z;              // b*8 + c
    const int OX  = blockIdx.x * 64;
    const int OY  = blockIdx.y * 64;
    const int I0x = (OX >> 2) - 5;
    const int I0y = (OY >> 2) - 5;

    const float* xb = x + (size_t)bc * (H * W);

    // ---- V-phase: 512 items = 32 padded cols x 16 row-groups ----
    // Item (c, rg): out rows 4*rg+p, halo col c; reads input rows
    // I0y+rg+j (j=0..11) at col I0x+c. Lanes c=27..31 are padding (masked).
    const bool interior = (I0x >= 0) & (I0x + 27 <= W) & (I0y >= 0) & (I0y + 27 <= H);
#pragma unroll
    for (int it = 0; it < 2; ++it) {
        int t  = tid + it * 256;
        int c  = t & 31;
        int rg = t >> 5;
        int cc = c < 27 ? c : 26;            // keep padding lanes in-bounds
        float a0 = 0.f, a1 = 0.f, a2 = 0.f, a3 = 0.f;
        if (interior) {
            const float* p = xb + (I0y + rg) * W + (I0x + cc);
#pragma unroll
            for (int j = 0; j < 12; ++j) {
                float v = p[j * W];
                a0 = fmaf(BASE48[4 * j + 3], v, a0);
                a1 = fmaf(BASE48[4 * j + 2], v, a1);
                a2 = fmaf(BASE48[4 * j + 1], v, a2);
                a3 = fmaf(BASE48[4 * j + 0], v, a3);
            }
        } else {
            int ix = I0x + cc;
#pragma unroll
            for (int j = 0; j < 12; ++j) {
                int iy = I0y + rg + j;
                float v = 0.0f;
                if ((unsigned)iy < (unsigned)H && (unsigned)ix < (unsigned)W)
                    v = xb[iy * W + ix];
                a0 = fmaf(BASE48[4 * j + 3], v, a0);
                a1 = fmaf(BASE48[4 * j + 2], v, a1);
                a2 = fmaf(BASE48[4 * j + 1], v, a2);
                a3 = fmaf(BASE48[4 * j + 0], v, a3);
            }
        }
        if (c < 27) {
            vtmp[4 * rg + 0][c] = a0;
            vtmp[4 * rg + 1][c] = a1;
            vtmp[4 * rg + 2][c] = a2;
            vtmp[4 * rg + 3][c] = a3;
        }
    }
    __syncthreads();

    // ---- H-phase: 256 items = 64 rows x 4 chunks of 16 out cols ----
    // Item (r, g): window = vtmp[r][4g .. 4g+15] (4x b128); computes out cols
    // OX+16g .. OX+16g+15 of out row OY+r; stores 4x v4f (64 B/thread).
    {
        int r = tid >> 2;
        int g = tid & 3;
        float win[16];
        *(v4f*)&win[0]  = *(const v4f*)&vtmp[r][4 * g + 0];
        *(v4f*)&win[4]  = *(const v4f*)&vtmp[r][4 * g + 4];
        *(v4f*)&win[8]  = *(const v4f*)&vtmp[r][4 * g + 8];
        *(v4f*)&win[12] = *(const v4f*)&vtmp[r][4 * g + 12];
        size_t rowbase = (size_t)bc * (OH * OW) + (size_t)(OY + r) * OW + (OX + 16 * g);
#pragma unroll
        for (int k = 0; k < 4; ++k) {
            float b0 = 0.f, b1 = 0.f, b2 = 0.f, b3 = 0.f;
#pragma unroll
            for (int j = 0; j < 12; ++j) {
                float v = win[k + j];      // static index (k,j unrolled)
                b0 = fmaf(BASE48[4 * j + 3], v, b0);
                b1 = fmaf(BASE48[4 * j + 2], v, b1);
                b2 = fmaf(BASE48[4 * j + 1], v, b2);
                b3 = fmaf(BASE48[4 * j + 0], v, b3);
            }
            v4f r4 = {b0, b1, b2, b3};
            *(v4f*)&out[rowbase + 4 * k] = r4;
        }
    }
}

extern "C" void kernel_launch(void* const* d_in, const int* in_sizes, int n_in,
                              void* d_out, int out_size, void* d_ws, size_t ws_size,
                              hipStream_t stream) {
    const float* x = (const float*)d_in[0];
    float* out = (float*)d_out;
    dim3 grid(8, 8, 128);   // 64x64 tiles over 512x512, z = B*C = 128
    dim3 block(256);
    upfirdn4_vh_kernel<<<grid, block, 0, stream>>>(x, out);
}

// Round 7
// 31.964 us; speedup vs baseline: 1.5641x; 1.5641x over previous
//
#include <hip/hip_runtime.h>

typedef float v4f __attribute__((ext_vector_type(4)));

// 45-tap palindromic filter, padded to 48 with zeros so every phase uses a
// uniform 12-tap loop: out phase p uses weight BASE48[4*j + 3 - p].
constexpr float BASE48[48] = {
    -0.00463495665f, -0.00363442646f, 3.84904063e-18f, 0.00576678319f, 0.0108358664f,
    0.010198079f, -9.31747402e-18f, -0.0175033181f, -0.0317660068f, -0.0284531643f,
    1.85181518e-17f, 0.0442450253f, 0.0771733386f, 0.067055491f, -2.85299239e-17f,
    -0.101548683f, -0.178708388f, -0.160004642f, 3.61741232e-17f, 0.287940558f,
    0.625431459f, 0.8970676f, 1.00107877f, 0.8970676f, 0.625431459f, 0.287940558f,
    3.61741232e-17f, -0.160004642f, -0.178708388f, -0.101548683f, -2.85299239e-17f,
    0.067055491f, 0.0771733386f, 0.0442450253f, 1.85181518e-17f, -0.0284531643f,
    -0.0317660068f, -0.0175033181f, -9.31747402e-18f, 0.010198079f, 0.0108358664f,
    0.00576678319f, 3.84904063e-18f, -0.00363442646f, -0.00463495665f,
    0.0f, 0.0f, 0.0f
};

__device__ __forceinline__ void fma4(v4f& a, float w, const v4f& v) {
    a.x = fmaf(w, v.x, a.x);
    a.y = fmaf(w, v.y, a.y);
    a.z = fmaf(w, v.z, a.z);
    a.w = fmaf(w, v.w, a.w);
}

// One block = 64x64 output tile of one (b,c) image.
//   H-phase: read input ROWS directly from global (contiguous, L1-cached;
//            halo is 27x27 = 2.9 KB/block) -> horizontal polyphase ->
//            tmp[27 input rows][64 out cols] in LDS.  (No staging, 1 barrier.)
//   V-phase: vertical polyphase from tmp (b128 reads), 4x4 patch per thread.
// Per axis: out o -> phase p = o&3, m = o>>2; input i = m - 5 + j, j in [0,12),
// weight BASE48[4*j + 3 - p]. Halo rows/cols = 64/4 + 11 = 27.
// LDS = 27*68*4 = 7.3 KB -> 8 blocks/CU (wave-capped). Grid 8192 = 4 rounds.
__launch_bounds__(256)
__global__ void upfirdn4_hg_kernel(const float* __restrict__ x,
                                   float* __restrict__ out) {
    constexpr int H = 128, W = 128, OW = 512, OH = 512;
    constexpr int TS = 68;           // tmp row stride (floats)

    __shared__ float tmp[27][TS];    // horizontal-pass result: 27 rows x 64 cols

    const int tid = threadIdx.x;
    const int bc  = blockIdx.z;              // b*8 + c
    const int OX  = blockIdx.x * 64;
    const int OY  = blockIdx.y * 64;
    const int I0x = (OX >> 2) - 5;
    const int I0y = (OY >> 2) - 5;

    const float* xb = x + (size_t)bc * (H * W);

    // ---- H-phase: 432 items = 27 input rows x 16 col-groups ----
    // Item (row, m): reads xb[I0y+row][I0x+m .. +m+11] (contiguous), computes
    // 4 output cols (phases 0..3), writes v4f to tmp[row][4m].
    const bool interior = (I0x >= 0) & (I0x + 27 <= W) & (I0y >= 0) & (I0y + 27 <= H);
    for (int t = tid; t < 27 * 16; t += 256) {
        int row = t >> 4;
        int m   = t & 15;
        float a0 = 0.f, a1 = 0.f, a2 = 0.f, a3 = 0.f;
        if (interior) {
            const float* p = xb + (I0y + row) * W + (I0x + m);
#pragma unroll
            for (int j = 0; j < 12; ++j) {
                float v = p[j];
                a0 = fmaf(BASE48[4 * j + 3], v, a0);
                a1 = fmaf(BASE48[4 * j + 2], v, a1);
                a2 = fmaf(BASE48[4 * j + 1], v, a2);
                a3 = fmaf(BASE48[4 * j + 0], v, a3);
            }
        } else {
            int iy = I0y + row;
            bool vrow = (unsigned)iy < (unsigned)H;
            const float* p = xb + (vrow ? iy : 0) * W;
#pragma unroll
            for (int j = 0; j < 12; ++j) {
                int ix = I0x + m + j;
                bool ok = vrow && ((unsigned)ix < (unsigned)W);
                float v = ok ? p[ix] : 0.0f;
                a0 = fmaf(BASE48[4 * j + 3], v, a0);
                a1 = fmaf(BASE48[4 * j + 2], v, a1);
                a2 = fmaf(BASE48[4 * j + 1], v, a2);
                a3 = fmaf(BASE48[4 * j + 0], v, a3);
            }
        }
        v4f r4 = {a0, a1, a2, a3};
        *(v4f*)&tmp[row][m << 2] = r4;
    }
    __syncthreads();

    // ---- V-phase: 256 items = 16 row-groups x 16 col-groups ----
    // Thread (m, oc): out rows 4m+p, cols oc..oc+3; reads tmp rows [m, m+12)
    // at col oc — 12 b128 LDS reads shared across the 4 phases.
    {
        int m  = tid >> 4;
        int oc = (tid & 15) << 2;
        v4f acc0 = {0, 0, 0, 0}, acc1 = {0, 0, 0, 0};
        v4f acc2 = {0, 0, 0, 0}, acc3 = {0, 0, 0, 0};
#pragma unroll
        for (int j = 0; j < 12; ++j) {
            v4f v = *(const v4f*)&tmp[m + j][oc];
            fma4(acc0, BASE48[4 * j + 3], v);
            fma4(acc1, BASE48[4 * j + 2], v);
            fma4(acc2, BASE48[4 * j + 1], v);
            fma4(acc3, BASE48[4 * j + 0], v);
        }
        size_t base = (size_t)bc * (OH * OW) + (size_t)(OY + (m << 2)) * OW + (OX + oc);
        *(v4f*)&out[base]          = acc0;
        *(v4f*)&out[base + OW]     = acc1;
        *(v4f*)&out[base + 2 * OW] = acc2;
        *(v4f*)&out[base + 3 * OW] = acc3;
    }
}

extern "C" void kernel_launch(void* const* d_in, const int* in_sizes, int n_in,
                              void* d_out, int out_size, void* d_ws, size_t ws_size,
                              hipStream_t stream) {
    const float* x = (const float*)d_in[0];
    float* out = (float*)d_out;
    dim3 grid(8, 8, 128);   // 64x64 tiles over 512x512, z = B*C = 128
    dim3 block(256);
    upfirdn4_hg_kernel<<<grid, block, 0, stream>>>(x, out);
}